// Round 9
// baseline (39048.987 us; speedup 1.0000x reference)
//
#include <hip/hip_runtime.h>
#include <math.h>

#define B_   64
#define T_   256
#define OUTD 1216
#define NBLK 64

typedef unsigned short ushort_t;
typedef unsigned int   uint32;
typedef unsigned long long u64;
typedef __attribute__((ext_vector_type(8))) short bfrag;   // 8 bf16
typedef __attribute__((ext_vector_type(4))) float f32x4;
typedef __attribute__((ext_vector_type(4))) unsigned short us4;

#define SCOPE_AGT __HIP_MEMORY_SCOPE_AGENT

__device__ __forceinline__ float sigmoidf_(float x) { return 1.0f / (1.0f + __expf(-x)); }
__device__ __forceinline__ float softplusf_(float x) { return (x > 20.0f) ? x : log1pf(__expf(x)); }
__device__ __forceinline__ ushort_t f2bf(float f) {
    uint32 u = __float_as_uint(f);
    u += 0x7fffu + ((u >> 16) & 1u);
    return (ushort_t)(u >> 16);
}
__device__ __forceinline__ float bf2f(ushort_t u) { return __uint_as_float(((uint32)u) << 16); }

// ---------------------------------------------------------------------------
// sc1 write-through + address-renaming scheme (rounds 6-8, proven):
// cross-block activations (emb_sw/det_sw/obs_sw, time-indexed so never
// re-written) are sc1-STORED to the coherent point; readers use plain cached
// loads on fresh addresses. Weights stay L2-resident, no fences ever.
// ---------------------------------------------------------------------------
union U16 { u64 q[2]; bfrag bv; f32x4 fv; };
union U8  { u64 q; us4 v4; };

__device__ __forceinline__ void stc8(void* p, u64 v) {
    __hip_atomic_store((u64*)p, v, __ATOMIC_RELAXED, SCOPE_AGT);
}
__device__ __forceinline__ void stc16b(void* p, bfrag v) {
    U16 u; u.bv = v; stc8(p, u.q[0]); stc8((u64*)p + 1, u.q[1]);
}

// ---------------------------------------------------------------------------
// kwprep: one-time weight conversion (+ zero the gsync area).
// ---------------------------------------------------------------------------
__global__ void kwprep(const float* __restrict__ Wih, const float* __restrict__ Whh,
                       const float* __restrict__ Wp1, const float* __restrict__ Wq1,
                       const float* __restrict__ Wp2, const float* __restrict__ Wq2,
                       const float* __restrict__ Wsa,
                       ushort_t* Wih_b, ushort_t* Whh_b, ushort_t* Wp1_b, ushort_t* Wq1_b,
                       ushort_t* W2sw, ushort_t* Wsasw, unsigned* gsync) {
    int stride = gridDim.x * blockDim.x;
    int gid = blockIdx.x * blockDim.x + threadIdx.x;
    for (int i = gid; i < 4096; i += stride) gsync[i] = 0u;
    for (int i = gid; i < 3072 * 1024; i += stride) Wih_b[i] = f2bf(Wih[i]);
    for (int i = gid; i < 3072 * 1024; i += stride) Whh_b[i] = f2bf(Whh[i]);
    for (int i = gid; i < 512 * 1024; i += stride) Wp1_b[i] = f2bf(Wp1[i]);
    for (int i = gid; i < 512 * 2048; i += stride) Wq1_b[i] = f2bf(Wq1[i]);
    for (int i = gid; i < 65536; i += stride) {
        int head = i >> 15, g = (i >> 9) & 63, o = (i >> 3) & 63, ii = i & 7;
        const float* src = head ? Wq2 : Wp2;
        W2sw[i] = f2bf(src[o * 512 + g * 8 + ii]);
    }
    for (int i = gid; i < 98304; i += stride) {
        int g = i >> 13, j = (i >> 3) & 1023, ii = i & 7;
        Wsasw[i] = f2bf(Wsa[j * 96 + g * 8 + ii]);
    }
}

// ---------------------------------------------------------------------------
// All-to-all flag barrier (round 9): each block sc1-stores its epoch to its
// OWN 128B-spaced flag; ONE WAVE polls all 64 flags (one per lane) until all
// >= ep. No central counter, no publish fan-out hop — the chain is just
// store-RTT + one poll period. Monotone flags are race-safe against blocks
// running ahead. vmcnt(0) before arrival drains this block's sc1 data stores.
// ---------------------------------------------------------------------------
__device__ __forceinline__ void gbar(unsigned* gs, int blk, unsigned& ep) {
    asm volatile("s_waitcnt vmcnt(0)" ::: "memory");
    __syncthreads();
    ++ep;
    if (threadIdx.x < 64) {
        if (threadIdx.x == 0)
            __hip_atomic_store(gs + 64 + blk * 32, ep, __ATOMIC_RELAXED, SCOPE_AGT);
        while (__hip_atomic_load(gs + 64 + (int)threadIdx.x * 32,
                                 __ATOMIC_RELAXED, SCOPE_AGT) < ep)
            __builtin_amdgcn_s_sleep(1);
    }
    __syncthreads();
}

// ---------------------------------------------------------------------------
// krssm: whole rollout, 64 blocks x 512 threads, TWO barriers per step:
//   A)  GRU, j-split (block owns 16 j, all 64 rows)      -> bar
//   BC) row-split (block owns batch row blk): pm1/qm1 via n=1 MFMA from
//       LDS-staged det/obs, heads+stats+emb all in-block  -> bar
// Fusing B+C kills the third all-to-all (pm1/qm1 now live in LDS only).
// ---------------------------------------------------------------------------
__global__ __launch_bounds__(512, 1) void krssm(
        const float* __restrict__ obs, const float* __restrict__ act,
        const float* __restrict__ n_p, const float* __restrict__ n_q,
        const float* __restrict__ Wsa, const float* __restrict__ bsa,
        const ushort_t* __restrict__ Wih, const ushort_t* __restrict__ Whh,
        const float* __restrict__ bih, const float* __restrict__ bhh,
        const ushort_t* __restrict__ Wp1b, const float* __restrict__ bp1,
        const ushort_t* __restrict__ Wq1b, const float* __restrict__ bq1,
        const ushort_t* __restrict__ W2sw, const ushort_t* __restrict__ Wsasw,
        const float* __restrict__ bp2, const float* __restrict__ bq2,
        ushort_t* emb_sw, ushort_t* obs_sw, ushort_t* det_sw,
        float* det_fp0, float* det_fp1,
        float* out, unsigned* gsync) {
    __shared__ float red[2 * 24 * 256];   // 48 KB, reused by all phases
    const int tid = threadIdx.x;
    const int blk = blockIdx.x;
    unsigned ep = 0;

    // ---- prologue (round 8, unchanged) ----
    if (tid < 256) {
        const int b = blk;
        const int j0 = tid * 4;
        const float* arow_ = act + (size_t)b * T_ * 64;
        float accp[4];
#pragma unroll
        for (int jj = 0; jj < 4; ++jj) {
            int j = j0 + jj;
            float acc = bsa[j];
            const float* w = Wsa + j * 96 + 32;
#pragma unroll 8
            for (int c = 0; c < 64; ++c) acc += arow_[c] * w[c];
            accp[jj] = fmaxf(acc, 0.f);
        }
        U8 u;
#pragma unroll
        for (int jj = 0; jj < 4; ++jj) u.v4[jj] = f2bf(accp[jj]);
        size_t eoff = ((size_t)(j0 >> 3) * 64 + b) * 8 + (j0 & 7);
        stc8(emb_sw + eoff, u.q);
        stc8(det_sw + eoff, 0ull);
        *(f32x4*)(det_fp0 + blk * 1024 + tid * 4) = (f32x4){0.f, 0.f, 0.f, 0.f};
    } else if (tid < 384) {   // swizzle obs(:, t=0, :) — row blk
        int g = tid - 256;
        const float* src = obs + (size_t)blk * T_ * 1024 + g * 8;
        bfrag v;
#pragma unroll
        for (int i = 0; i < 8; ++i) v[i] = (short)f2bf(src[i]);
        stc16b(obs_sw + ((size_t)g * 64 + blk) * 8, v);
    }
    gbar(gsync, blk, ep);

    float* dfp_in = det_fp0;
    float* dfp_out = det_fp1;

#pragma unroll 1
    for (int t = 0; t < T_; ++t) {
        const ushort_t* emb_t = emb_sw + ((size_t)t << 16);
        const ushort_t* det_t = det_sw + ((size_t)t << 16);
        ushort_t*       det_n = det_sw + ((size_t)(t + 1) << 16);
        const ushort_t* obs_t = obs_sw + ((size_t)t << 16);

        // ================= phase A: GRU (round 8, unchanged) ================
        {
            const int lane = tid & 63, w = tid >> 6;     // w in [0,8)
            const int kw = w >> 1, bw = w & 1;
            const int m = lane & 15, quad = lane >> 4;
            const int j0 = blk * 16;

            f32x4 acc[2][3][2];
#pragma unroll
            for (int a2 = 0; a2 < 2; ++a2)
#pragma unroll
                for (int g = 0; g < 3; ++g)
#pragma unroll
                    for (int n = 0; n < 2; ++n) acc[a2][g][n] = (f32x4){0.f, 0.f, 0.f, 0.f};

            const int kb0 = kw * 256;
            const ushort_t* arow[2][3];
#pragma unroll
            for (int g = 0; g < 3; ++g) {
                arow[0][g] = Wih + (size_t)(g * 1024 + j0 + m) * 1024 + kb0 + quad * 8;
                arow[1][g] = Whh + (size_t)(g * 1024 + j0 + m) * 1024 + kb0 + quad * 8;
            }
            const ushort_t* bx = emb_t + ((kb0 >> 3) + quad) * 512 + m * 8;
            const ushort_t* bh = det_t + ((kb0 >> 3) + quad) * 512 + m * 8;

#pragma unroll
            for (int it = 0; it < 8; ++it) {
                bfrag a[2][3], vx[2], vh[2];
#pragma unroll
                for (int g = 0; g < 3; ++g) {
                    a[0][g] = *(const bfrag*)(arow[0][g] + it * 32);
                    a[1][g] = *(const bfrag*)(arow[1][g] + it * 32);
                }
#pragma unroll
                for (int n = 0; n < 2; ++n) {
                    vx[n] = *(const bfrag*)(bx + it * 2048 + (bw * 2 + n) * 128);
                    vh[n] = *(const bfrag*)(bh + it * 2048 + (bw * 2 + n) * 128);
                }
#pragma unroll
                for (int g = 0; g < 3; ++g)
#pragma unroll
                    for (int n = 0; n < 2; ++n) {
                        acc[0][g][n] = __builtin_amdgcn_mfma_f32_16x16x32_bf16(a[0][g], vx[n], acc[0][g][n], 0, 0, 0);
                        acc[1][g][n] = __builtin_amdgcn_mfma_f32_16x16x32_bf16(a[1][g], vh[n], acc[1][g][n], 0, 0, 0);
                    }
            }

            if (kw & 1) {
                float* dst = red + (kw >> 1) * 6144;
#pragma unroll
                for (int a2 = 0; a2 < 2; ++a2)
#pragma unroll
                    for (int g = 0; g < 3; ++g)
#pragma unroll
                        for (int n = 0; n < 2; ++n)
                            *(f32x4*)(dst + ((a2 * 3 + g) * 4 + bw * 2 + n) * 256 + lane * 4) = acc[a2][g][n];
            }
            __syncthreads();
            if (!(kw & 1)) {
                float* dst = red + (kw >> 1) * 6144;
#pragma unroll
                for (int a2 = 0; a2 < 2; ++a2)
#pragma unroll
                    for (int g = 0; g < 3; ++g)
#pragma unroll
                        for (int n = 0; n < 2; ++n) {
                            float* pp = dst + ((a2 * 3 + g) * 4 + bw * 2 + n) * 256 + lane * 4;
                            f32x4 v = *(const f32x4*)pp;
                            v += acc[a2][g][n];
                            *(f32x4*)pp = v;
                        }
            }
            __syncthreads();

            if (tid < 256) {   // gate phase
                int b = tid >> 2, jq = tid & 3;
                int nt = b >> 4, bl = b & 15;
                int lsrc = (jq * 16 + bl) * 4;
                float gg[2][3][4];
#pragma unroll
                for (int a2 = 0; a2 < 2; ++a2)
#pragma unroll
                    for (int g = 0; g < 3; ++g) {
                        f32x4 v0 = *(const f32x4*)(red + ((a2 * 3 + g) * 4 + nt) * 256 + lsrc);
                        f32x4 v1 = *(const f32x4*)(red + 6144 + ((a2 * 3 + g) * 4 + nt) * 256 + lsrc);
#pragma unroll
                        for (int i = 0; i < 4; ++i) gg[a2][g][i] = v0[i] + v1[i];
                    }
                f32x4 bi[3], bh2[3];
#pragma unroll
                for (int g = 0; g < 3; ++g) {
                    bi[g] = *(const f32x4*)(bih + g * 1024 + j0 + jq * 4);
                    bh2[g] = *(const f32x4*)(bhh + g * 1024 + j0 + jq * 4);
                }
                f32x4 h4;
                U8 dq;
#pragma unroll
                for (int i = 0; i < 4; ++i) {
                    int j = j0 + jq * 4 + i;
                    float r = sigmoidf_(gg[0][0][i] + bi[0][i] + gg[1][0][i] + bh2[0][i]);
                    float z = sigmoidf_(gg[0][1][i] + bi[1][i] + gg[1][1][i] + bh2[1][i]);
                    float n = tanhf(gg[0][2][i] + bi[2][i] + r * (gg[1][2][i] + bh2[2][i]));
                    float hp = dfp_in[j * 64 + b];
                    float h = (1.f - z) * n + z * hp;
                    h4[i] = h;
                    dq.v4[i] = f2bf(h);
                    dfp_out[j * 64 + b] = h;
                }
                *(f32x4*)(out + ((size_t)b * T_ + t) * OUTD + j0 + jq * 4) = h4;
                int kbase = j0 + jq * 4;
                stc8(det_n + ((size_t)(kbase >> 3) * 64 + b) * 8 + (kbase & 7), dq.q);
            }
        }
        gbar(gsync, blk, ep);

        // ========== phase BC: row-split pm/qm (MFMA n=1) + heads + emb ======
        {
            ushort_t* s_det = (ushort_t*)red;            // [1024] bf16
            ushort_t* s_obs = (ushort_t*)(red + 512);    // [1024] bf16
            float* s_pm = red + 1024;                    // [512]
            float* s_qm = red + 1536;                    // [512]
            float* ph   = red + 2048;                    // [256]
            float* s_in = red + 2304;                    // [0,32) stoch, [32,96) act
            ushort_t* ush = (ushort_t*)(red + 2432);     // [1024] emb staging
            const int b = blk;

            // stage: det/obs row b -> LDS; obs(t+1) swizzle; act(t+1)
            if (tid < 128) {
                bfrag v = *(const bfrag*)(det_n + ((size_t)tid * 64 + b) * 8);
                *(bfrag*)(s_det + tid * 8) = v;
            } else if (tid < 256) {
                int g = tid - 128;
                bfrag v = *(const bfrag*)(obs_t + ((size_t)g * 64 + b) * 8);
                *(bfrag*)(s_obs + g * 8) = v;
            } else if (tid < 384) {
                if (t + 1 < T_) {
                    int g = tid - 256;
                    const float* src0 = obs + ((size_t)b * T_ + t + 1) * 1024 + g * 8;
                    bfrag v0;
#pragma unroll
                    for (int i = 0; i < 8; ++i) v0[i] = (short)f2bf(src0[i]);
                    stc16b(obs_sw + ((size_t)(t + 1) << 16) + ((size_t)g * 64 + b) * 8, v0);
                }
            } else if (tid < 448) {
                if (t + 1 < T_) s_in[32 + (tid - 384)] = act[((size_t)b * T_ + t + 1) * 64 + (tid - 384)];
            }
            __syncthreads();

            // pm1/qm1 via n=1 MFMA: wave w handles j-blocks {w, w+8, w+16, w+24}
            // of both pm (K=1024) and qm (K=2048). B-operand: det/obs broadcast
            // from LDS (lanes 0-15 same addr); only C column 0 (lanes m==0) used.
            {
                const int lane = tid & 63, w = tid >> 6;
                const int m = lane & 15, quad = lane >> 4;
#pragma unroll
                for (int rep = 0; rep < 4; ++rep) {
                    int j0 = (w + rep * 8) * 16;
                    f32x4 acc = (f32x4){0.f, 0.f, 0.f, 0.f};
                    const ushort_t* ar = Wp1b + (size_t)(j0 + m) * 1024 + quad * 8;
#pragma unroll
                    for (int kb = 0; kb < 32; ++kb) {
                        bfrag a = *(const bfrag*)(ar + kb * 32);
                        bfrag bv = *(const bfrag*)(s_det + kb * 32 + quad * 8);
                        acc = __builtin_amdgcn_mfma_f32_16x16x32_bf16(a, bv, acc, 0, 0, 0);
                    }
                    if (m == 0) {
                        int jr = j0 + quad * 4;
#pragma unroll
                        for (int i = 0; i < 4; ++i)
                            s_pm[jr + i] = fmaxf(acc[i] + bp1[jr + i], 0.f);
                    }
                }
#pragma unroll
                for (int rep = 0; rep < 4; ++rep) {
                    int j0 = (w + rep * 8) * 16;
                    f32x4 acc = (f32x4){0.f, 0.f, 0.f, 0.f};
                    const ushort_t* ar = Wq1b + (size_t)(j0 + m) * 2048 + quad * 8;
#pragma unroll
                    for (int kb = 0; kb < 64; ++kb) {
                        bfrag a = *(const bfrag*)(ar + kb * 32);
                        const ushort_t* bs = (kb < 32) ? (s_det + kb * 32)
                                                       : (s_obs + (kb - 32) * 32);
                        bfrag bv = *(const bfrag*)(bs + quad * 8);
                        acc = __builtin_amdgcn_mfma_f32_16x16x32_bf16(a, bv, acc, 0, 0, 0);
                    }
                    if (m == 0) {
                        int jr = j0 + quad * 4;
#pragma unroll
                        for (int i = 0; i < 4; ++i)
                            s_qm[jr + i] = fmaxf(acc[i] + bq1[jr + i], 0.f);
                    }
                }
            }
            __syncthreads();

            if (tid < 256) {   // head GEMV, K-split x2
                int kh = tid >> 7, head = (tid >> 6) & 1, o = tid & 63;
                const ushort_t* wp = W2sw + head * 32768 + o * 8 + kh * 32 * 512;
                const float* hv = (head ? s_qm : s_pm) + kh * 256;
                float acc2 = 0.f;
#pragma unroll 8
                for (int g = 0; g < 32; ++g) {
                    bfrag w8 = *(const bfrag*)(wp + g * 512);
#pragma unroll
                    for (int i2 = 0; i2 < 8; ++i2) acc2 += hv[g * 8 + i2] * bf2f((ushort_t)w8[i2]);
                }
                ph[kh * 128 + head * 64 + o] = acc2;
            }
            __syncthreads();
            if (tid < 64) {    // stats: combine K-halves + bias inline
                int s = tid & 31, isq = tid >> 5;
                const float* bias = isq ? bq2 : bp2;
                float mean = ph[isq * 64 + s] + ph[128 + isq * 64 + s] + bias[s];
                float raw  = ph[isq * 64 + 32 + s] + ph[128 + isq * 64 + 32 + s] + bias[32 + s];
                float sd = softplusf_(raw) + 1e-5f;
                float noise = (isq ? n_q : n_p)[((size_t)b * T_ + t) * 32 + s];
                float st = mean + sd * noise;
                float* o = out + ((size_t)b * T_ + t) * OUTD + 1024 + isq * 96;
                o[s] = mean;
                o[32 + s] = sd;
                o[64 + s] = st;
                if (isq) s_in[s] = st;
            }
            __syncthreads();
            if (t + 1 < T_) {   // emb(t+1): 2 j per thread -> LDS staging
                int j0e = tid * 2;
                float acc2[2];
                acc2[0] = bsa[j0e];
                acc2[1] = bsa[j0e + 1];
#pragma unroll
                for (int g = 0; g < 12; ++g) {
#pragma unroll
                    for (int jj = 0; jj < 2; ++jj) {
                        bfrag w8 = *(const bfrag*)(Wsasw + ((size_t)g * 1024 + j0e + jj) * 8);
#pragma unroll
                        for (int i2 = 0; i2 < 8; ++i2) acc2[jj] += s_in[g * 8 + i2] * bf2f((ushort_t)w8[i2]);
                    }
                }
                ush[j0e] = f2bf(fmaxf(acc2[0], 0.f));
                ush[j0e + 1] = f2bf(fmaxf(acc2[1], 0.f));
            }
            __syncthreads();
            if (t + 1 < T_ && tid < 128) {
                bfrag v = *(const bfrag*)(ush + tid * 8);
                stc16b(emb_sw + ((size_t)(t + 1) << 16) + ((size_t)tid * 64 + b) * 8, v);
            }
        }
        gbar(gsync, blk, ep);

        // swap block-private det_fp ping-pong
        float* tf = dfp_in; dfp_in = dfp_out; dfp_out = tf;
    }
}

extern "C" void kernel_launch(void* const* d_in, const int* in_sizes, int n_in,
                              void* d_out, int out_size, void* d_ws, size_t ws_size,
                              hipStream_t stream) {
    const float* obs = (const float*)d_in[0];
    const float* act = (const float*)d_in[1];
    const float* n_p = (const float*)d_in[2];
    const float* n_q = (const float*)d_in[3];
    const float* W_sa = (const float*)d_in[4];
    const float* b_sa = (const float*)d_in[5];
    const float* W_ih = (const float*)d_in[6];
    const float* b_ih = (const float*)d_in[7];
    const float* W_hh = (const float*)d_in[8];
    const float* b_hh = (const float*)d_in[9];
    const float* Wp1 = (const float*)d_in[10];
    const float* bp1 = (const float*)d_in[11];
    const float* Wp2 = (const float*)d_in[12];
    const float* bp2 = (const float*)d_in[13];
    const float* Wq1 = (const float*)d_in[14];
    const float* bq1 = (const float*)d_in[15];
    const float* Wq2 = (const float*)d_in[16];
    const float* bq2 = (const float*)d_in[17];
    float* out = (float*)d_out;

    if (ws_size < (size_t)114 * 1024 * 1024) return;

    char* p = (char*)d_ws;
    ushort_t* Wih_b = (ushort_t*)p;  p += (size_t)3145728 * 2;
    ushort_t* Whh_b = (ushort_t*)p;  p += (size_t)3145728 * 2;
    ushort_t* Wp1_b = (ushort_t*)p;  p += (size_t)524288 * 2;
    ushort_t* Wq1_b = (ushort_t*)p;  p += (size_t)1048576 * 2;
    ushort_t* W2sw  = (ushort_t*)p;  p += (size_t)65536 * 2;
    ushort_t* Wsasw = (ushort_t*)p;  p += (size_t)98304 * 2;
    float* det_fp0 = (float*)p; p += (size_t)65536 * 4;
    float* det_fp1 = (float*)p; p += (size_t)65536 * 4;
    unsigned* gsync = (unsigned*)p; p += (size_t)16384 * 4;
    ushort_t* emb_sw = (ushort_t*)p; p += (size_t)256 * 65536 * 2;   // [t][...]
    ushort_t* obs_sw = (ushort_t*)p; p += (size_t)256 * 65536 * 2;   // [t][...]
    ushort_t* det_sw = (ushort_t*)p; p += (size_t)257 * 65536 * 2;   // [t][...]

    kwprep<<<1024, 256, 0, stream>>>(W_ih, W_hh, Wp1, Wq1, Wp2, Wq2, W_sa,
                                     Wih_b, Whh_b, Wp1_b, Wq1_b, W2sw, Wsasw, gsync);
    krssm<<<NBLK, 512, 0, stream>>>(obs, act, n_p, n_q, W_sa, b_sa,
                                    Wih_b, Whh_b, b_ih, b_hh,
                                    Wp1_b, bp1, Wq1_b, bq1,
                                    W2sw, Wsasw, bp2, bq2,
                                    emb_sw, obs_sw, det_sw,
                                    det_fp0, det_fp1, out, gsync);
}